// Round 3
// baseline (25228.580 us; speedup 1.0000x reference)
//
#include <hip/hip_runtime.h>
#include <math.h>

#define Bd 4
#define Cd 512
#define Hd 48
#define Wd 48
#define HWd (Hd * Wd)          // 2304
#define Nd (Bd * HWd)          // 9216
#define BN_EPS 1e-5f

// ---------------- tiled fp32 linear (1x1 conv) ----------------
// out[n][o] = sum_c in_tok[n][c] * w[o][c] + bias[o]
template<bool IN_BCHW, bool OUT_BCHW>
__global__ __launch_bounds__(256) void linear_k(const float* __restrict__ in,
                                                const float* __restrict__ w,
                                                const float* __restrict__ bias,
                                                float* __restrict__ out) {
    __shared__ float Asub[16][68];     // [c_local][token]
    __shared__ float Bsub[64][17];     // [o_local][c_local]

    const int tid = threadIdx.x;
    const int tx = tid & 15;
    const int ty = tid >> 4;
    const int n0 = blockIdx.x * 64;
    const int o0 = blockIdx.y * 64;
    const int b  = n0 / HWd;           // tile never straddles batch (2304 % 64 == 0)
    const int hw0 = n0 % HWd;

    float acc[4][4] = {};

    for (int k0 = 0; k0 < Cd; k0 += 16) {
        if (IN_BCHW) {
            int r = tid >> 6;
            int col = tid & 63;
            #pragma unroll
            for (int i = 0; i < 4; ++i) {
                int c_l = r * 4 + i;
                Asub[c_l][col] = in[(size_t)(b * Cd + k0 + c_l) * HWd + hw0 + col];
            }
        } else {
            int c_l = tid & 15;
            int t0 = tid >> 4;
            #pragma unroll
            for (int i = 0; i < 4; ++i) {
                int t = t0 + 16 * i;
                Asub[c_l][t] = in[(size_t)(n0 + t) * Cd + k0 + c_l];
            }
        }
        {
            int c_l = tid & 15;
            int o_l = tid >> 4;
            #pragma unroll
            for (int i = 0; i < 4; ++i) {
                int o = o_l + 16 * i;
                Bsub[o][c_l] = w[(size_t)(o0 + o) * Cd + k0 + c_l];
            }
        }
        __syncthreads();
        #pragma unroll
        for (int k = 0; k < 16; ++k) {
            float4 av = *(const float4*)&Asub[k][tx * 4];
            float a[4] = {av.x, av.y, av.z, av.w};
            float bb[4];
            #pragma unroll
            for (int j = 0; j < 4; ++j) bb[j] = Bsub[ty * 4 + j][k];
            #pragma unroll
            for (int i = 0; i < 4; ++i)
                #pragma unroll
                for (int j = 0; j < 4; ++j)
                    acc[i][j] = fmaf(a[i], bb[j], acc[i][j]);
        }
        __syncthreads();
    }

    #pragma unroll
    for (int j = 0; j < 4; ++j) {
        float bj = bias[o0 + ty * 4 + j];
        #pragma unroll
        for (int i = 0; i < 4; ++i) acc[i][j] += bj;
    }

    if (OUT_BCHW) {
        #pragma unroll
        for (int j = 0; j < 4; ++j) {
            int o = o0 + ty * 4 + j;
            size_t base = (size_t)(b * Cd + o) * HWd + hw0 + tx * 4;
            #pragma unroll
            for (int i = 0; i < 4; ++i) out[base + i] = acc[i][j];
        }
    } else {
        #pragma unroll
        for (int i = 0; i < 4; ++i) {
            int n = n0 + tx * 4 + i;
            #pragma unroll
            for (int j = 0; j < 4; ++j)
                out[(size_t)n * Cd + o0 + ty * 4 + j] = acc[i][j];
        }
    }
}

// ---------------- flash attention (fp32, register state) ----------------
// enh[i] = sum_j softmax_j(lhs[i].rhs[j]) * xt[j]
// 8 query rows / block; each 32-lane group owns one row.
// m, l, O all in REGISTERS (uniform / lane-private) — no cross-lane LDS state.
__global__ __launch_bounds__(256) void attn_k(const float* __restrict__ lhs,
                                              const float* __restrict__ rhs,
                                              const float* __restrict__ xt,
                                              float* __restrict__ enh) {
    __shared__ float q_lds[8][512];    // read-only after barrier

    const int tid = threadIdx.x;
    const int i0 = blockIdx.x * 8;
    const int q = tid >> 5;            // 0..7
    const int jl = tid & 31;

    for (int i = tid; i < 8 * 512; i += 256)
        ((float*)q_lds)[i] = lhs[(size_t)i0 * 512 + i];
    __syncthreads();

    float o_reg[16];
    #pragma unroll
    for (int k = 0; k < 16; ++k) o_reg[k] = 0.f;
    float m = -INFINITY;               // uniform across the 32-lane group
    float l = 0.f;                     // uniform across the 32-lane group

    for (int jt = 0; jt < Nd; jt += 32) {
        const float4* r4 = (const float4*)(rhs + (size_t)(jt + jl) * 512);
        const float4* q4 = (const float4*)(q_lds[q]);
        float s = 0.f;
        #pragma unroll 8
        for (int c = 0; c < 128; ++c) {
            float4 a = q4[c];
            float4 v = r4[c];
            s = fmaf(a.x, v.x, s); s = fmaf(a.y, v.y, s);
            s = fmaf(a.z, v.z, s); s = fmaf(a.w, v.w, s);
        }
        float mt = s;
        #pragma unroll
        for (int off = 16; off; off >>= 1) mt = fmaxf(mt, __shfl_xor(mt, off, 32));
        float m_new = fmaxf(m, mt);
        float p = __expf(s - m_new);
        float ps = p;
        #pragma unroll
        for (int off = 16; off; off >>= 1) ps += __shfl_xor(ps, off, 32);
        float corr = __expf(m - m_new);    // exp(-inf)=0 on first tile
        l = l * corr + ps;
        m = m_new;

        const float* xrow = xt + (size_t)jt * 512;
        #pragma unroll 4
        for (int k = 0; k < 16; ++k) {
            int c = jl + 32 * k;
            float o = o_reg[k] * corr;
            #pragma unroll
            for (int j = 0; j < 32; ++j) {
                float pj = __shfl(p, j, 32);
                o = fmaf(pj, xrow[(size_t)j * 512 + c], o);
            }
            o_reg[k] = o;
        }
    }
    float linv = 1.f / l;
    #pragma unroll
    for (int k = 0; k < 16; ++k) {
        int c = jl + 32 * k;
        enh[(size_t)(i0 + q) * 512 + c] = o_reg[k] * linv;
    }
}

// ---------------- BN stats (per channel, double accumulation) ----------------
__global__ __launch_bounds__(256) void bnstats_k(const float* __restrict__ y,
                                                 const float* __restrict__ gamma,
                                                 const float* __restrict__ beta,
                                                 float* __restrict__ stats) {
    const int c = blockIdx.x;
    const int tid = threadIdx.x;
    double s = 0.0, sq = 0.0;
    for (int b = 0; b < Bd; ++b) {
        const float* p = y + (size_t)(b * Cd + c) * HWd;
        for (int i = tid; i < HWd; i += 256) {
            double v = (double)p[i];
            s += v;
            sq += v * v;
        }
    }
    #pragma unroll
    for (int off = 32; off; off >>= 1) {
        s  += __shfl_xor(s, off, 64);
        sq += __shfl_xor(sq, off, 64);
    }
    __shared__ double ss[4], sqs[4];
    int wid = tid >> 6;
    if ((tid & 63) == 0) { ss[wid] = s; sqs[wid] = sq; }
    __syncthreads();
    if (tid == 0) {
        double S = ss[0] + ss[1] + ss[2] + ss[3];
        double Q = sqs[0] + sqs[1] + sqs[2] + sqs[3];
        double mean = S / (double)Nd;
        double var = Q / (double)Nd - mean * mean;
        float inv = (float)(1.0 / sqrt(var + (double)BN_EPS));
        float sc = gamma[c] * inv;
        stats[c] = sc;
        stats[Cd + c] = beta[c] - (float)mean * sc;
    }
}

// ---------------- BN apply + ReLU: reads y (ws), writes d_out ----------------
__global__ __launch_bounds__(256) void bnapply_k(const float* __restrict__ y,
                                                 const float* __restrict__ stats,
                                                 float* __restrict__ out) {
    int idx = blockIdx.x * 256 + threadIdx.x;
    if (idx >= Bd * Cd * HWd) return;
    int c = (idx / HWd) % Cd;
    float v = fmaf(y[idx], stats[c], stats[Cd + c]);
    out[idx] = fmaxf(v, 0.f);
}

extern "C" void kernel_launch(void* const* d_in, const int* in_sizes, int n_in,
                              void* d_out, int out_size, void* d_ws, size_t ws_size,
                              hipStream_t stream) {
    const float* x     = (const float*)d_in[0];
    const float* depth = (const float*)d_in[1];
    const float* w_rgb = (const float*)d_in[2];
    const float* b_rgb = (const float*)d_in[3];
    const float* w_lhs = (const float*)d_in[4];
    const float* b_lhs = (const float*)d_in[5];
    const float* w_rhs = (const float*)d_in[6];
    const float* b_rhs = (const float*)d_in[7];
    const float* w_dec = (const float*)d_in[8];
    const float* b_dec = (const float*)d_in[9];
    const float* gamma = (const float*)d_in[10];
    const float* beta  = (const float*)d_in[11];
    float* out = (float*)d_out;

    float* ws  = (float*)d_ws;
    const size_t NC = (size_t)Nd * Cd;
    float* ws0 = ws;            // xt, later y (BCHW)
    float* ws1 = ws + NC;       // lhs, later stats
    float* ws2 = ws + 2 * NC;   // rhs

    dim3 gGemm(Nd / 64, Cd / 64);
    linear_k<true, false><<<gGemm, 256, 0, stream>>>(x, w_rgb, b_rgb, ws0);
    linear_k<true, false><<<gGemm, 256, 0, stream>>>(depth, w_lhs, b_lhs, ws1);
    linear_k<true, false><<<gGemm, 256, 0, stream>>>(depth, w_rhs, b_rhs, ws2);

    // attention output (token-major, exactly out_size floats) staged in d_out
    attn_k<<<Nd / 8, 256, 0, stream>>>(ws1, ws2, ws0, out);

    // decoder y (BCHW) -> ws0 (xt dead)
    linear_k<false, true><<<gGemm, 256, 0, stream>>>(out, w_dec, b_dec, ws0);

    // BN stats -> ws1 (lhs dead); apply reads ws0, writes d_out
    bnstats_k<<<Cd, 256, 0, stream>>>(ws0, gamma, beta, ws1);
    bnapply_k<<<(Bd * Cd * HWd + 255) / 256, 256, 0, stream>>>(ws0, ws1, out);
}

// Round 4
// 1104.630 us; speedup vs baseline: 22.8389x; 22.8389x over previous
//
#include <hip/hip_runtime.h>
#include <math.h>

#define Bd 4
#define Cd 512
#define Hd 48
#define Wd 48
#define HWd (Hd * Wd)          // 2304
#define Nd (Bd * HWd)          // 9216
#define BN_EPS 1e-5f

#define QBLK 64
#define KBLK 128
#define NKS 2
#define KSLEN (Nd / NKS)       // 4608
#define AITERS (KSLEN / KBLK)  // 36

typedef _Float16 half8 __attribute__((ext_vector_type(8)));
typedef _Float16 h2 __attribute__((ext_vector_type(2)));
typedef float f32x16 __attribute__((ext_vector_type(16)));

__device__ inline void gload_lds16(const void* g, void* l) {
    __builtin_amdgcn_global_load_lds((const __attribute__((address_space(1))) void*)g,
                                     (__attribute__((address_space(3))) void*)l, 16, 0, 0);
}

// ---------------- tiled fp32 linear (1x1 conv), templated layouts ----------------
// INM: 0 = BCHW f32 input, 2 = ch-major f32 [Cd][Nd]
// OUTM: 0 = fp16 token-major [Nd][Cd], 1 = fp16 ch-major [Cd][Nd], 2 = f32 BCHW
template<int INM, int OUTM>
__global__ __launch_bounds__(256) void linear_k(const float* __restrict__ in,
                                                const float* __restrict__ w,
                                                const float* __restrict__ bias,
                                                void* __restrict__ outp) {
    __shared__ float Asub[16][68];
    __shared__ float Bsub[64][17];

    const int tid = threadIdx.x;
    const int tx = tid & 15;
    const int ty = tid >> 4;
    const int n0 = blockIdx.x * 64;
    const int o0 = blockIdx.y * 64;
    const int b  = n0 / HWd;
    const int hw0 = n0 % HWd;

    float acc[4][4] = {};

    for (int k0 = 0; k0 < Cd; k0 += 16) {
        {
            int r = tid >> 6;
            int col = tid & 63;
            #pragma unroll
            for (int i = 0; i < 4; ++i) {
                int c_l = r * 4 + i;
                if (INM == 0)
                    Asub[c_l][col] = in[(size_t)(b * Cd + k0 + c_l) * HWd + hw0 + col];
                else
                    Asub[c_l][col] = in[(size_t)(k0 + c_l) * Nd + n0 + col];
            }
        }
        {
            int c_l = tid & 15;
            int o_l = tid >> 4;
            #pragma unroll
            for (int i = 0; i < 4; ++i) {
                int o = o_l + 16 * i;
                Bsub[o][c_l] = w[(size_t)(o0 + o) * Cd + k0 + c_l];
            }
        }
        __syncthreads();
        #pragma unroll
        for (int k = 0; k < 16; ++k) {
            float4 av = *(const float4*)&Asub[k][tx * 4];
            float a[4] = {av.x, av.y, av.z, av.w};
            float bb[4];
            #pragma unroll
            for (int j = 0; j < 4; ++j) bb[j] = Bsub[ty * 4 + j][k];
            #pragma unroll
            for (int i = 0; i < 4; ++i)
                #pragma unroll
                for (int j = 0; j < 4; ++j)
                    acc[i][j] = fmaf(a[i], bb[j], acc[i][j]);
        }
        __syncthreads();
    }

    #pragma unroll
    for (int j = 0; j < 4; ++j) {
        float bj = bias[o0 + ty * 4 + j];
        #pragma unroll
        for (int i = 0; i < 4; ++i) acc[i][j] += bj;
    }

    if (OUTM == 0) {
        _Float16* o16 = (_Float16*)outp;
        #pragma unroll
        for (int i = 0; i < 4; ++i)
            #pragma unroll
            for (int j = 0; j < 4; ++j)
                o16[(size_t)(n0 + tx * 4 + i) * Cd + o0 + ty * 4 + j] = (_Float16)acc[i][j];
    } else if (OUTM == 1) {
        _Float16* o16 = (_Float16*)outp;
        #pragma unroll
        for (int j = 0; j < 4; ++j)
            #pragma unroll
            for (int i = 0; i < 4; ++i)
                o16[(size_t)(o0 + ty * 4 + j) * Nd + n0 + tx * 4 + i] = (_Float16)acc[i][j];
    } else {
        float* of = (float*)outp;
        #pragma unroll
        for (int j = 0; j < 4; ++j) {
            int o = o0 + ty * 4 + j;
            size_t base = (size_t)(b * Cd + o) * HWd + hw0 + tx * 4;
            #pragma unroll
            for (int i = 0; i < 4; ++i) of[base + i] = acc[i][j];
        }
    }
}

// ---------------- MFMA flash attention (fp16 inputs, fp32 accum) ----------------
// Swapped-operand: S^T = mfma(K, Q)  (col = query = lane&31)
//                  O^T = mfma(xtT, P^T) (col = query, row = channel)
// Partials per key-split ks written unnormalized with (m, l) for LSE merge.
__global__ __launch_bounds__(512, 2) void attn_mfma_k(
    const _Float16* __restrict__ lhsH,   // [Nd][512]
    const _Float16* __restrict__ rhsH,   // [Nd][512]
    const _Float16* __restrict__ xtT,    // [512][Nd]
    float* __restrict__ part,            // [NKS][512][Nd]
    float* __restrict__ marr,            // [NKS][Nd]
    float* __restrict__ larr) {          // [NKS][Nd]
    __shared__ _Float16 Kl[KBLK * 512];  // 128 KB, swizzled rows (1KB each)
    __shared__ _Float16 Pl[QBLK * KBLK]; // 16 KB, swizzled rows (256B each)
    __shared__ float m_s[QBLK], l_s[QBLK], corr_s[QBLK];
    __shared__ float tm_s[4][QBLK], ls_s[4][QBLK];

    const int tid = threadIdx.x;
    const int wave = tid >> 6;
    const int lane = tid & 63;
    const int l31 = lane & 31;
    const int hi32 = lane >> 5;

    const int nqb = Nd / QBLK;           // 144
    const int qb = blockIdx.x % nqb;
    const int ks = blockIdx.x / nqb;
    const int q0 = qb * QBLK;
    const int k0g = ks * KSLEN;

    const int kt = wave & 3;             // key sub-tile (QK phase)
    const int qg = wave >> 2;            // query tile (QK phase)

    // Q fragments in registers (this wave's 32-query tile, full d=512)
    half8 qf[32];
    {
        const _Float16* qrow = lhsH + (size_t)(q0 + qg * 32 + l31) * 512 + hi32 * 8;
        #pragma unroll
        for (int f = 0; f < 32; ++f)
            qf[f] = *(const half8*)(qrow + f * 16);
    }

    f32x16 o_acc[2][2];
    #pragma unroll
    for (int a = 0; a < 2; ++a)
        #pragma unroll
        for (int b = 0; b < 2; ++b)
            #pragma unroll
            for (int r = 0; r < 16; ++r) o_acc[a][b][r] = 0.f;

    if (tid < QBLK) { m_s[tid] = -INFINITY; l_s[tid] = 0.f; }
    __syncthreads();

    for (int it = 0; it < AITERS; ++it) {
        const int kb = k0g + it * KBLK;

        // ---- stage K tile: 128 rows x 1KB, swizzled via pre-swizzled source
        #pragma unroll
        for (int i = 0; i < 16; ++i) {
            int base = wave * 16384 + i * 1024;
            int Lb = base + lane * 16;
            int row = Lb >> 10;
            int inb = Lb & 1023;
            int sinb = inb ^ ((row & 7) << 4);
            gload_lds16((const char*)(rhsH + (size_t)(kb + row) * 512) + sinb,
                        (char*)Kl + base);
        }
        __syncthreads();   // staging complete (vmcnt drained by barrier)

        float m_old = m_s[qg * 32 + l31];

        // ---- QK^T (swapped): S^T frag, 32 MFMAs over d=512
        f32x16 s;
        #pragma unroll
        for (int r = 0; r < 16; ++r) s[r] = 0.f;
        {
            const int row = kt * 32 + l31;
            const char* krow = (const char*)Kl + row * 1024;
            const int swz = (row & 7) << 4;
            #pragma unroll
            for (int f = 0; f < 32; ++f) {
                half8 a = *(const half8*)(krow + ((32 * f + 16 * hi32) ^ swz));
                s = __builtin_amdgcn_mfma_f32_32x32x16_f16(a, qf[f], s, 0, 0, 0);
            }
        }

        // ---- tile max (this wave's 32 keys for query l31)
        float tmax = s[0];
        #pragma unroll
        for (int r = 1; r < 16; ++r) tmax = fmaxf(tmax, s[r]);
        tmax = fmaxf(tmax, __shfl_xor(tmax, 32));
        if (lane < 32) tm_s[kt][qg * 32 + lane] = tmax;
        __syncthreads();

        // ---- new max, corr, P = exp(s - m_new), write P to LDS
        float mn = m_old;
        #pragma unroll
        for (int t = 0; t < 4; ++t) mn = fmaxf(mn, tm_s[t][qg * 32 + l31]);
        float corr = __expf(m_old - mn);

        float psum = 0.f;
        {
            const int qrow = qg * 32 + l31;
            char* prow = (char*)Pl + qrow * 256;
            const int swz = (qrow & 7) << 4;
            #pragma unroll
            for (int g = 0; g < 4; ++g) {
                float p0 = __expf(s[4 * g + 0] - mn);
                float p1 = __expf(s[4 * g + 1] - mn);
                float p2 = __expf(s[4 * g + 2] - mn);
                float p3 = __expf(s[4 * g + 3] - mn);
                psum += (p0 + p1) + (p2 + p3);
                int keyb = (kt * 32 + 8 * g + 4 * hi32) * 2;
                *(h2*)(prow + ((keyb)     ^ swz)) = (h2){(_Float16)p0, (_Float16)p1};
                *(h2*)(prow + ((keyb + 4) ^ swz)) = (h2){(_Float16)p2, (_Float16)p3};
            }
        }
        psum += __shfl_xor(psum, 32);
        if (lane < 32) {
            ls_s[kt][qg * 32 + lane] = psum;
            if (kt == 0) corr_s[qg * 32 + lane] = corr;
        }
        __syncthreads();

        // ---- state update (kt==0 waves own it)
        if (kt == 0 && lane < 32) {
            int ql = qg * 32 + lane;
            m_s[ql] = mn;
            l_s[ql] = l_s[ql] * corr +
                      ls_s[0][ql] + ls_s[1][ql] + ls_s[2][ql] + ls_s[3][ql];
        }

        // ---- rescale O^T, then PV (wave owns 64-channel slice)
        float c0v = corr_s[l31];
        float c1v = corr_s[32 + l31];
        #pragma unroll
        for (int cht = 0; cht < 2; ++cht)
            #pragma unroll
            for (int r = 0; r < 16; ++r) {
                o_acc[cht][0][r] *= c0v;
                o_acc[cht][1][r] *= c1v;
            }

        {
            const int swz = (l31 & 7) << 4;
            #pragma unroll
            for (int kf = 0; kf < 8; ++kf) {
                int inb = (32 * kf + 16 * hi32) ^ swz;
                half8 pb0 = *(const half8*)((char*)Pl + l31 * 256 + inb);
                half8 pb1 = *(const half8*)((char*)Pl + (32 + l31) * 256 + inb);
                #pragma unroll
                for (int cht = 0; cht < 2; ++cht) {
                    const _Float16* xp = xtT + (size_t)(wave * 64 + cht * 32 + l31) * Nd
                                       + (kb + kf * 16 + hi32 * 8);
                    half8 xa = *(const half8*)xp;
                    o_acc[cht][0] = __builtin_amdgcn_mfma_f32_32x32x16_f16(xa, pb0, o_acc[cht][0], 0, 0, 0);
                    o_acc[cht][1] = __builtin_amdgcn_mfma_f32_32x32x16_f16(xa, pb1, o_acc[cht][1], 0, 0, 0);
                }
            }
        }
        __syncthreads();   // P/K consumed; safe to restage next iter
    }

    // ---- epilogue: write unnormalized partials + (m, l)
    #pragma unroll
    for (int cht = 0; cht < 2; ++cht)
        #pragma unroll
        for (int qt = 0; qt < 2; ++qt)
            #pragma unroll
            for (int r = 0; r < 16; ++r) {
                int ch = wave * 64 + cht * 32 + (r & 3) + 8 * (r >> 2) + 4 * hi32;
                int q = q0 + qt * 32 + l31;
                part[((size_t)ks * Cd + ch) * Nd + q] = o_acc[cht][qt][r];
            }
    if (kt == 0 && lane < 32) {
        int ql = qg * 32 + lane;
        marr[(size_t)ks * Nd + q0 + ql] = m_s[ql];
        larr[(size_t)ks * Nd + q0 + ql] = l_s[ql];
    }
}

// ---------------- LSE merge of the NKS key-split partials (in-place into part0) --
__global__ __launch_bounds__(256) void merge_k(float* __restrict__ part,
                                               const float* __restrict__ marr,
                                               const float* __restrict__ larr) {
    int idx = blockIdx.x * 256 + threadIdx.x;
    if (idx >= Cd * Nd) return;
    int q = idx % Nd;
    float m0 = marr[q], m1 = marr[Nd + q];
    float mm = fmaxf(m0, m1);
    float w0 = __expf(m0 - mm), w1 = __expf(m1 - mm);
    float L = larr[q] * w0 + larr[Nd + q] * w1;
    part[idx] = (part[idx] * w0 + part[(size_t)Cd * Nd + idx] * w1) / L;
}

// ---------------- BN stats (per channel, double accumulation) ----------------
__global__ __launch_bounds__(256) void bnstats_k(const float* __restrict__ y,
                                                 const float* __restrict__ gamma,
                                                 const float* __restrict__ beta,
                                                 float* __restrict__ stats) {
    const int c = blockIdx.x;
    const int tid = threadIdx.x;
    double s = 0.0, sq = 0.0;
    for (int b = 0; b < Bd; ++b) {
        const float* p = y + (size_t)(b * Cd + c) * HWd;
        for (int i = tid; i < HWd; i += 256) {
            double v = (double)p[i];
            s += v;
            sq += v * v;
        }
    }
    #pragma unroll
    for (int off = 32; off; off >>= 1) {
        s  += __shfl_xor(s, off, 64);
        sq += __shfl_xor(sq, off, 64);
    }
    __shared__ double ss[4], sqs[4];
    int wid = tid >> 6;
    if ((tid & 63) == 0) { ss[wid] = s; sqs[wid] = sq; }
    __syncthreads();
    if (tid == 0) {
        double S = ss[0] + ss[1] + ss[2] + ss[3];
        double Q = sqs[0] + sqs[1] + sqs[2] + sqs[3];
        double mean = S / (double)Nd;
        double var = Q / (double)Nd - mean * mean;
        float inv = (float)(1.0 / sqrt(var + (double)BN_EPS));
        float sc = gamma[c] * inv;
        stats[c] = sc;
        stats[Cd + c] = beta[c] - (float)mean * sc;
    }
}

__global__ __launch_bounds__(256) void bnapply_k(const float* __restrict__ y,
                                                 const float* __restrict__ stats,
                                                 float* __restrict__ out) {
    int idx = blockIdx.x * 256 + threadIdx.x;
    if (idx >= Bd * Cd * HWd) return;
    int c = (idx / HWd) % Cd;
    float v = fmaf(y[idx], stats[c], stats[Cd + c]);
    out[idx] = fmaxf(v, 0.f);
}

extern "C" void kernel_launch(void* const* d_in, const int* in_sizes, int n_in,
                              void* d_out, int out_size, void* d_ws, size_t ws_size,
                              hipStream_t stream) {
    const float* x     = (const float*)d_in[0];
    const float* depth = (const float*)d_in[1];
    const float* w_rgb = (const float*)d_in[2];
    const float* b_rgb = (const float*)d_in[3];
    const float* w_lhs = (const float*)d_in[4];
    const float* b_lhs = (const float*)d_in[5];
    const float* w_rhs = (const float*)d_in[6];
    const float* b_rhs = (const float*)d_in[7];
    const float* w_dec = (const float*)d_in[8];
    const float* b_dec = (const float*)d_in[9];
    const float* gamma = (const float*)d_in[10];
    const float* beta  = (const float*)d_in[11];
    float* out = (float*)d_out;

    char* wsb = (char*)d_ws;
    const size_t H_BYTES = (size_t)Nd * Cd * 2;      // 9,437,184
    _Float16* lhsH = (_Float16*)wsb;
    _Float16* rhsH = (_Float16*)(wsb + H_BYTES);
    _Float16* xtT  = (_Float16*)(wsb + 2 * H_BYTES);
    float* part = (float*)(wsb + 3 * H_BYTES);       // 2 x Cd x Nd f32
    float* marr = part + (size_t)NKS * Cd * Nd;      // 2 x Nd
    float* larr = marr + (size_t)NKS * Nd;
    float* stats = larr + (size_t)NKS * Nd;
    float* ybuf = part + (size_t)Cd * Nd;            // reuse part1 after merge

    dim3 gGemm(Nd / 64, Cd / 64);
    linear_k<0, 0><<<gGemm, 256, 0, stream>>>(depth, w_lhs, b_lhs, lhsH);
    linear_k<0, 0><<<gGemm, 256, 0, stream>>>(depth, w_rhs, b_rhs, rhsH);
    linear_k<0, 1><<<gGemm, 256, 0, stream>>>(x, w_rgb, b_rgb, xtT);

    attn_mfma_k<<<(Nd / QBLK) * NKS, 512, 0, stream>>>(lhsH, rhsH, xtT, part, marr, larr);

    merge_k<<<((size_t)Cd * Nd + 255) / 256, 256, 0, stream>>>(part, marr, larr);

    linear_k<2, 2><<<gGemm, 256, 0, stream>>>(part, w_dec, b_dec, ybuf);

    bnstats_k<<<Cd, 256, 0, stream>>>(ybuf, gamma, beta, stats);
    bnapply_k<<<(Bd * Cd * HWd + 255) / 256, 256, 0, stream>>>(ybuf, stats, out);
}